// Round 3
// baseline (123.344 us; speedup 1.0000x reference)
//
#include <hip/hip_runtime.h>

// AdaptiveVoxelization — fused single-dispatch streaming kernel.
//  d_out (float32, concatenated): [0,12M) coors [N,3] zyx/-1; [12M,15M)
//  centers [3,R^3]; [15M,16M) center_mask as 0/1.
//
// R2 lesson: __builtin_nontemporal_* needs clang ext_vector_type, not
// HIP_vector_type float4. FP op chains IDENTICAL to the R1 passing version
// (__f*_rn, no contraction) — validity flips cost ~2000 absmax, do not touch.

#define RES 100
#define R3 (RES * RES * RES)
#define NCG (R3 / 4)  // 250,000 center groups of 4 (4 | RES -> never cross a row)

typedef float f32x4 __attribute__((ext_vector_type(4)));

// JAX linspace(start, stop, RES, endpoint=True) element k (lerp form, exact
// endpoint at k==RES-1). Matched R1-passing numerics.
__device__ __forceinline__ float lin_val(float start, float stop, int k) {
  if (k == RES - 1) return stop;
  float t = __fdiv_rn((float)k, (float)(RES - 1));
  return __fadd_rn(__fmul_rn(start, __fsub_rn(1.0f, t)),
                   __fmul_rn(stop, t));
}

__global__ __launch_bounds__(256) void adaptive_voxel_fused(
    const f32x4* __restrict__ pts, float* __restrict__ out,
    int n4 /* point groups of 4 */, int nbVox /* blocks in voxel part */) {
  int b = blockIdx.x;
  if (b < nbVox) {
    // ---- voxelize: 4 points/thread, dwordx4 in, 3x dwordx4 out ----
    int t = b * 256 + threadIdx.x;
    if (t >= n4) return;
    const f32x4* pp = pts + (size_t)4 * t;
    float o[12];
#pragma unroll
    for (int k = 0; k < 4; ++k) {
      f32x4 p = __builtin_nontemporal_load(&pp[k]);
      float c0 = floorf(__fdiv_rn(__fsub_rn(p.x, -50.0f), 0.1f));
      float c1 = floorf(__fdiv_rn(__fsub_rn(p.y, -50.0f), 0.1f));
      float c2 = floorf(__fdiv_rn(__fsub_rn(p.z, -1.0f), 0.2f));
      // grid = round((hi-lo)/vs) in f32 = (2000, 1000, 20) exactly
      bool valid = (c0 >= 0.0f) && (c0 < 2000.0f) &&
                   (c1 >= 0.0f) && (c1 < 1000.0f) &&
                   (c2 >= 0.0f) && (c2 < 20.0f);
      o[3 * k]     = valid ? c2 : -1.0f;  // zyx order
      o[3 * k + 1] = valid ? c1 : -1.0f;
      o[3 * k + 2] = valid ? c0 : -1.0f;
    }
    f32x4* cp = (f32x4*)out + (size_t)3 * t;
#pragma unroll
    for (int k = 0; k < 3; ++k) {
      f32x4 v = {o[4 * k], o[4 * k + 1], o[4 * k + 2], o[4 * k + 3]};
      __builtin_nontemporal_store(v, cp + k);
    }
  } else {
    // ---- adaptive centers: 4 consecutive i2/thread, float4 per plane ----
    int q = (b - nbVox) * 256 + threadIdx.x;
    if (q >= NCG) return;
    int j0 = 4 * q;
    int i0 = j0 / (RES * RES);
    int rem = j0 - i0 * (RES * RES);
    int i1 = rem / RES;
    int i2b = rem - i1 * RES;  // multiple of 4; i2b..i2b+3 stay in-row
    float c0 = lin_val(-50.0f, 150.0f, i0);
    float c1 = lin_val(-50.0f, 50.0f, i1);
    float s01 = __fadd_rn(__fmul_rn(c0, c0), __fmul_rn(c1, c1));
    // norm_c = sqrt(150^2+50^2+3^2) = sqrt(25009), exact-integer f32 corner
    float nc = __fsqrt_rn(25009.0f);
    float nc2 = __fmul_rn(nc, nc);
    f32x4 xs, ys, zs, ms;
#pragma unroll
    for (int k = 0; k < 4; ++k) {
      float c2 = lin_val(-1.0f, 3.0f, i2b + k);
      float s = __fadd_rn(s01, __fmul_rn(c2, c2));  // same association as R1
      float nrm = __fsqrt_rn(s);
      float sf = __fdiv_rn(__fmul_rn(nrm, nrm), nc2);  // quadratic mode
      float scale = __fadd_rn(1.0f, __fmul_rn(sf, 25.0f));
      float x0 = __fmul_rn(c0, scale);
      float x1 = __fmul_rn(c1, scale);
      float x2 = __fmul_rn(c2, scale);
      bool m = (x0 >= -50.0f) && (x0 <= 150.0f) &&
               (x1 >= -50.0f) && (x1 <= 50.0f) &&
               (x2 >= -1.0f) && (x2 <= 3.0f);
      xs[k] = x0; ys[k] = x1; zs[k] = x2; ms[k] = m ? 1.0f : 0.0f;
    }
    // centers base = out + 3*N floats; planes are R3 floats = NCG float4s
    f32x4* cx = (f32x4*)(out + (size_t)12 * n4);
    __builtin_nontemporal_store(xs, cx + q);
    __builtin_nontemporal_store(ys, cx + NCG + q);
    __builtin_nontemporal_store(zs, cx + 2 * NCG + q);
    __builtin_nontemporal_store(ms, cx + 3 * NCG + q);
  }
}

extern "C" void kernel_launch(void* const* d_in, const int* in_sizes, int n_in,
                              void* d_out, int out_size, void* d_ws, size_t ws_size,
                              hipStream_t stream) {
  const f32x4* pts = (const f32x4*)d_in[0];
  int n4 = in_sizes[0] / 16;             // groups of 4 points ([N,4] f32 -> /4 /4)
  float* out = (float*)d_out;
  int nbVox = (n4 + 255) / 256;          // 3907 for N=4M
  int nbCen = (NCG + 255) / 256;         // 977
  adaptive_voxel_fused<<<nbVox + nbCen, 256, 0, stream>>>(pts, out, n4, nbVox);
}

// Round 4
// 111.286 us; speedup vs baseline: 1.1083x; 1.1083x over previous
//
#include <hip/hip_runtime.h>

// AdaptiveVoxelization — fused single-dispatch streaming kernel.
//  d_out (float32, concatenated): [0,12M) coors [N,3] zyx/-1; [12M,15M)
//  centers [3,R^3]; [15M,16M) center_mask as 0/1.
//
// R3 lesson: nontemporal hints REGRESSED (110 -> 123 us total; kernel
// ~24 -> ~37 us). nt bypasses L2 write-combining on CDNA. R4 = R3 minus
// all nt builtins (single-variable experiment). Plain f32x4 stores still
// emit global_store_dwordx4.
// FP op chains IDENTICAL to the R1 passing version (__f*_rn, no
// contraction) — validity flips cost ~2000 absmax, do not touch.

#define RES 100
#define R3 (RES * RES * RES)
#define NCG (R3 / 4)  // 250,000 center groups of 4 (4 | RES -> never cross a row)

typedef float f32x4 __attribute__((ext_vector_type(4)));

// JAX linspace(start, stop, RES, endpoint=True) element k (lerp form, exact
// endpoint at k==RES-1). Matched R1-passing numerics.
__device__ __forceinline__ float lin_val(float start, float stop, int k) {
  if (k == RES - 1) return stop;
  float t = __fdiv_rn((float)k, (float)(RES - 1));
  return __fadd_rn(__fmul_rn(start, __fsub_rn(1.0f, t)),
                   __fmul_rn(stop, t));
}

__global__ __launch_bounds__(256) void adaptive_voxel_fused(
    const f32x4* __restrict__ pts, float* __restrict__ out,
    int n4 /* point groups of 4 */, int nbVox /* blocks in voxel part */) {
  int b = blockIdx.x;
  if (b < nbVox) {
    // ---- voxelize: 4 points/thread, dwordx4 in, 3x dwordx4 out ----
    int t = b * 256 + threadIdx.x;
    if (t >= n4) return;
    const f32x4* pp = pts + (size_t)4 * t;
    float o[12];
#pragma unroll
    for (int k = 0; k < 4; ++k) {
      f32x4 p = pp[k];
      float c0 = floorf(__fdiv_rn(__fsub_rn(p.x, -50.0f), 0.1f));
      float c1 = floorf(__fdiv_rn(__fsub_rn(p.y, -50.0f), 0.1f));
      float c2 = floorf(__fdiv_rn(__fsub_rn(p.z, -1.0f), 0.2f));
      // grid = round((hi-lo)/vs) in f32 = (2000, 1000, 20) exactly
      bool valid = (c0 >= 0.0f) && (c0 < 2000.0f) &&
                   (c1 >= 0.0f) && (c1 < 1000.0f) &&
                   (c2 >= 0.0f) && (c2 < 20.0f);
      o[3 * k]     = valid ? c2 : -1.0f;  // zyx order
      o[3 * k + 1] = valid ? c1 : -1.0f;
      o[3 * k + 2] = valid ? c0 : -1.0f;
    }
    f32x4* cp = (f32x4*)out + (size_t)3 * t;
#pragma unroll
    for (int k = 0; k < 3; ++k) {
      f32x4 v = {o[4 * k], o[4 * k + 1], o[4 * k + 2], o[4 * k + 3]};
      cp[k] = v;
    }
  } else {
    // ---- adaptive centers: 4 consecutive i2/thread, float4 per plane ----
    int q = (b - nbVox) * 256 + threadIdx.x;
    if (q >= NCG) return;
    int j0 = 4 * q;
    int i0 = j0 / (RES * RES);
    int rem = j0 - i0 * (RES * RES);
    int i1 = rem / RES;
    int i2b = rem - i1 * RES;  // multiple of 4; i2b..i2b+3 stay in-row
    float c0 = lin_val(-50.0f, 150.0f, i0);
    float c1 = lin_val(-50.0f, 50.0f, i1);
    float s01 = __fadd_rn(__fmul_rn(c0, c0), __fmul_rn(c1, c1));
    // norm_c = sqrt(150^2+50^2+3^2) = sqrt(25009), exact-integer f32 corner
    float nc = __fsqrt_rn(25009.0f);
    float nc2 = __fmul_rn(nc, nc);
    f32x4 xs, ys, zs, ms;
#pragma unroll
    for (int k = 0; k < 4; ++k) {
      float c2 = lin_val(-1.0f, 3.0f, i2b + k);
      float s = __fadd_rn(s01, __fmul_rn(c2, c2));  // same association as R1
      float nrm = __fsqrt_rn(s);
      float sf = __fdiv_rn(__fmul_rn(nrm, nrm), nc2);  // quadratic mode
      float scale = __fadd_rn(1.0f, __fmul_rn(sf, 25.0f));
      float x0 = __fmul_rn(c0, scale);
      float x1 = __fmul_rn(c1, scale);
      float x2 = __fmul_rn(c2, scale);
      bool m = (x0 >= -50.0f) && (x0 <= 150.0f) &&
               (x1 >= -50.0f) && (x1 <= 50.0f) &&
               (x2 >= -1.0f) && (x2 <= 3.0f);
      xs[k] = x0; ys[k] = x1; zs[k] = x2; ms[k] = m ? 1.0f : 0.0f;
    }
    // centers base = out + 3*N floats; planes are R3 floats = NCG float4s
    f32x4* cx = (f32x4*)(out + (size_t)12 * n4);
    cx[q] = xs;
    cx[NCG + q] = ys;
    cx[2 * NCG + q] = zs;
    cx[3 * NCG + q] = ms;
  }
}

extern "C" void kernel_launch(void* const* d_in, const int* in_sizes, int n_in,
                              void* d_out, int out_size, void* d_ws, size_t ws_size,
                              hipStream_t stream) {
  const f32x4* pts = (const f32x4*)d_in[0];
  int n4 = in_sizes[0] / 16;             // groups of 4 points ([N,4] f32 -> /4 /4)
  float* out = (float*)d_out;
  int nbVox = (n4 + 255) / 256;          // 3907 for N=4M
  int nbCen = (NCG + 255) / 256;         // 977
  adaptive_voxel_fused<<<nbVox + nbCen, 256, 0, stream>>>(pts, out, n4, nbVox);
}